// Round 13
// baseline (351.961 us; speedup 1.0000x reference)
//
#include <hip/hip_runtime.h>
#include <hip/hip_bf16.h>

// ---------------- problem constants ----------------
namespace {
constexpr int Bb = 128, Nn = 12800, Ee = 262144;
constexpr int LAT = 256, HID = 128, FCH = 512, NRBF = 16;
constexpr int TE = 64;        // edges per block (divides 2048 = edges/graph)
constexpr int TSTRIDE = 1040; // activation-tile stride in bytes

// workspace offsets (floats)
constexpr int WS_L      = 0;        // B*9
constexpr int WS_LI     = 1152;     // B*9
constexpr int WS_SIG    = 2304;     // B
constexpr int WS_RBFW2  = 2432;     // 16*128
constexpr int WS_CVEC   = 4480;     // 128
constexpr int WS_HB     = 4608;     // 100*128
constexpr int WS_LATP   = 17408;    // B*512
constexpr int WS_PERT   = 82944;    // N*3
constexpr int WS_ALIGN  = 121344;   // N*3
constexpr int WS_SN     = 159744;   // N*3 (atomic)
constexpr int WS_GN     = 198144;   // N*3 (atomic)
constexpr int WS_PREDS  = 236544;   // N*3
constexpr int WS_BSUM   = 274944;   // B*3 (atomic)
constexpr int WS_CENTER = 275328;   // B*3 (atomic)
constexpr int WS_MINMAX = 275712;   // 6   (max x3, min x3)
// bf16 fragment-tiled weights (stored as ushort), float-index base:
constexpr int WS_W0T_F  = 276000;   // ushort[512*128]  (= 32768 floats)
constexpr int WS_W1T_F  = 308768;   // ushort[512*512]  (= 131072 floats)
}

typedef short bf16x8 __attribute__((ext_vector_type(8)));
typedef unsigned short u16x8 __attribute__((ext_vector_type(8)));
typedef float f32x4 __attribute__((ext_vector_type(4)));

static __device__ __forceinline__ unsigned short f2bf(float f) {
  unsigned int u = __float_as_uint(f);
  unsigned int r = (u + 0x7fffu + ((u >> 16) & 1u)) >> 16;
  return (unsigned short)r;
}
// single-instruction packed f32->bf16 pair: low16 = bf16(a), high16 = bf16(b)
static __device__ __forceinline__ unsigned int pk2bf(float a, float b) {
  unsigned int r;
  asm("v_cvt_pk_bf16_f32 %0, %1, %2" : "=v"(r) : "v"(a), "v"(b));
  return r;
}
static __device__ __forceinline__ float fastrcp(float x) {
  return __builtin_amdgcn_rcpf(x);
}

static __device__ __forceinline__ void make_lattice(
    const float* lengths, const float* angles, int b, float L[9], float Li[9]) {
  float a = lengths[b * 3 + 0], bl = lengths[b * 3 + 1], c = lengths[b * 3 + 2];
  const float d2r = 0.017453292519943295f;
  float al = angles[b * 3 + 0] * d2r, be = angles[b * 3 + 1] * d2r, ga = angles[b * 3 + 2] * d2r;
  float ca = cosf(al), cb = cosf(be), cg = cosf(ga), sa = sinf(al), sb = sinf(be);
  float val = (ca * cb - cg) / (sa * sb);
  val = fminf(1.f, fmaxf(-1.f, val));
  float gs = acosf(val);
  L[0] = a * sb;              L[1] = 0.f;                L[2] = a * cb;
  L[3] = -bl * sa * cosf(gs); L[4] = bl * sa * sinf(gs); L[5] = bl * ca;
  L[6] = 0.f;                 L[7] = 0.f;                L[8] = c;
  float det = L[0] * (L[4] * L[8] - L[5] * L[7])
            - L[1] * (L[3] * L[8] - L[5] * L[6])
            + L[2] * (L[3] * L[7] - L[4] * L[6]);
  float id = 1.f / det;
  Li[0] =  (L[4] * L[8] - L[5] * L[7]) * id;
  Li[1] = -(L[1] * L[8] - L[2] * L[7]) * id;
  Li[2] =  (L[1] * L[5] - L[2] * L[4]) * id;
  Li[3] = -(L[3] * L[8] - L[5] * L[6]) * id;
  Li[4] =  (L[0] * L[8] - L[2] * L[6]) * id;
  Li[5] = -(L[0] * L[5] - L[2] * L[3]) * id;
  Li[6] =  (L[3] * L[7] - L[4] * L[6]) * id;
  Li[7] = -(L[0] * L[7] - L[1] * L[6]) * id;
  Li[8] =  (L[0] * L[4] - L[1] * L[3]) * id;
}

static __device__ __forceinline__ void atomicMaxFloat(float* addr, float val) {
  int* ai = reinterpret_cast<int*>(addr);
  int old = *ai;
  while (__int_as_float(old) < val) {
    int assumed = old;
    old = atomicCAS(ai, assumed, __float_as_int(val));
    if (old == assumed) break;
  }
}
static __device__ __forceinline__ void atomicMinFloat(float* addr, float val) {
  int* ai = reinterpret_cast<int*>(addr);
  int old = *ai;
  while (__int_as_float(old) > val) {
    int assumed = old;
    old = atomicCAS(ai, assumed, __float_as_int(val));
    if (old == assumed) break;
  }
}

// ---------------- fused prologue: all mutually-independent prep work ----------------
// blocks   0..303 : zero accumulators, init MINMAX
// block      304  : lattice + sigma -> ws
// blocks 305..404 : hb = atom_emb @ bb_W
// block      405  : rbfW2 / cvec
// blocks 406..533 : lat_proj
// blocks 534..565 : cvtW0 (coalesced 16B writes)
// blocks 566..693 : cvtW1 (coalesced 16B writes)
// blocks 694..743 : per-node geometry (lattice recomputed inline per node)
__global__ __launch_bounds__(256) void k_pre(
    const float* lengths, const float* angles, const float* sigmas, const int* tsteps,
    const float* aemb, const float* bbW, const float* rbfW, const float* rbfb,
    const float* bbb, const float* latents, const float* scW0, const float* scb0,
    const float* scW1, const float* gtf, const float* noise, const int* batch,
    const int* atype, unsigned short* w0t, unsigned short* w1t, float* ws) {
  const int blk = blockIdx.x, t = threadIdx.x;
  if (blk < 304) {
    int gid = blk * 256 + t;
    if (gid < 2 * Nn * 3) ws[WS_SN + gid] = 0.f;
    else if (gid < 2 * Nn * 3 + 2 * Bb * 3) ws[WS_BSUM + (gid - 2 * Nn * 3)] = 0.f;
    else if (gid < 2 * Nn * 3 + 2 * Bb * 3 + 3) ws[WS_MINMAX + (gid - 2 * Nn * 3 - 2 * Bb * 3)] = -3.0e38f;
    else if (gid < 2 * Nn * 3 + 2 * Bb * 3 + 6) ws[WS_MINMAX + (gid - 2 * Nn * 3 - 2 * Bb * 3)] = 3.0e38f;
  } else if (blk == 304) {
    int b = t;
    if (b >= Bb) return;
    float L[9], Li[9];
    make_lattice(lengths, angles, b, L, Li);
#pragma unroll
    for (int i = 0; i < 9; ++i) {
      ws[WS_L + b * 9 + i] = L[i];
      ws[WS_LI + b * 9 + i] = Li[i];
    }
    ws[WS_SIG + b] = sigmas[tsteps[b]];
  } else if (blk < 405) {
    int tile = blk - 305;
    if (t < HID) {
      float acc = 0.f;
      for (int k = 0; k < HID; ++k) acc += aemb[tile * HID + k] * bbW[k * HID + t];
      ws[WS_HB + tile * HID + t] = acc;
    }
  } else if (blk == 405) {
    if (t < HID) {
      float accs[NRBF];
#pragma unroll
      for (int k = 0; k < NRBF; ++k) accs[k] = 0.f;
      float accb = 0.f;
      for (int m = 0; m < HID; ++m) {
        float w = bbW[m * HID + t];
#pragma unroll
        for (int k = 0; k < NRBF; ++k) accs[k] += rbfW[k * HID + m] * w;
        accb += rbfb[m] * w;
      }
#pragma unroll
      for (int k = 0; k < NRBF; ++k) ws[WS_RBFW2 + k * HID + t] = accs[k];
      ws[WS_CVEC + t] = accb + bbb[t];
    }
  } else if (blk < 534) {
    int b = blk - 406;
    __shared__ float lat[LAT];
    lat[t] = latents[b * LAT + t];
    __syncthreads();
    int c0 = 2 * t;
    float a0 = 0.f, a1 = 0.f;
    for (int m = 0; m < LAT; ++m) {
      float2 w = *reinterpret_cast<const float2*>(scW0 + (HID + m) * FCH + c0);
      float lm = lat[m];
      a0 += lm * w.x;
      a1 += lm * w.y;
    }
    ws[WS_LATP + b * FCH + c0] = a0 + scb0[c0];
    ws[WS_LATP + b * FCH + c0 + 1] = a1 + scb0[c0 + 1];
  } else if (blk < 566) {
    // cvtW0: thread id8 produces w0t[id8*8 .. id8*8+7] (one coalesced 16B store)
    int id8 = (blk - 534) * 256 + t;     // 0..8191
    int tile = id8 >> 6, lf = id8 & 63;  // tile = colTile*4 + kTile
    int colTile = tile >> 2, kTile = tile & 3;
    int col = colTile * 16 + (lf & 15);
    int kbase = kTile * 32 + (lf >> 4) * 8;
    u16x8 v;
#pragma unroll
    for (int e = 0; e < 8; ++e) v[e] = f2bf(scW0[(kbase + e) * FCH + col]);
    *(u16x8*)(w0t + id8 * 8) = v;
  } else if (blk < 694) {
    // cvtW1: thread id8 produces w1t[id8*8 .. id8*8+7]
    int id8 = (blk - 566) * 256 + t;     // 0..32767
    int tile = id8 >> 6, lf = id8 & 63;  // tile = colTile*16 + kTile
    int colTile = tile >> 4, kTile = tile & 15;
    int col = colTile * 16 + (lf & 15);
    int kbase = kTile * 32 + (lf >> 4) * 8;
    u16x8 v;
#pragma unroll
    for (int e = 0; e < 8; ++e) v[e] = f2bf(scW1[(kbase + e) * FCH + col]);
    *(u16x8*)(w1t + id8 * 8) = v;
  } else {
    // per-node geometry (former k_node), lattice recomputed inline
    int n = (blk - 694) * 256 + t;
    if (n >= Nn) return;
    int b = batch[n];
    float L[9], Li[9];
    make_lattice(lengths, angles, b, L, Li);
    float sig = sigmas[tsteps[b]];
    float f0 = gtf[n * 3], f1 = gtf[n * 3 + 1], f2 = gtf[n * 3 + 2];
    float cg[3], p0[3], fp[3], pe[3], fg[3], fd[3];
#pragma unroll
    for (int j = 0; j < 3; ++j) cg[j] = f0 * L[j] + f1 * L[3 + j] + f2 * L[6 + j];
#pragma unroll
    for (int j = 0; j < 3; ++j) p0[j] = cg[j] + sig * noise[n * 3 + j];
#pragma unroll
    for (int j = 0; j < 3; ++j) {
      float v = p0[0] * Li[j] + p0[1] * Li[3 + j] + p0[2] * Li[6 + j];
      fp[j] = v - floorf(v);
    }
#pragma unroll
    for (int j = 0; j < 3; ++j) pe[j] = fp[0] * L[j] + fp[1] * L[3 + j] + fp[2] * L[6 + j];
#pragma unroll
    for (int j = 0; j < 3; ++j) fg[j] = cg[0] * Li[j] + cg[1] * Li[3 + j] + cg[2] * Li[6 + j];
#pragma unroll
    for (int j = 0; j < 3; ++j) { float d = fg[j] - fp[j]; fd[j] = d - rintf(d); }
#pragma unroll
    for (int j = 0; j < 3; ++j) {
      ws[WS_PERT + n * 3 + j] = pe[j];
      ws[WS_ALIGN + n * 3 + j] = pe[j] + fd[0] * L[j] + fd[1] * L[3 + j] + fd[2] * L[6 + j];
    }
  }
}

// ---------------- the big fused MFMA edge kernel (transposed compute) ----------------
// D[wcol][edge] = mfma(A = W^T fragment, B = act^T fragment); weight tiles in
// ws are direct A-fragments. Activations in LDS in B-fragment tile order at
// TSTRIDE-byte tile stride. Every ds_read is lane*16B contiguous.
// Tile: 64 edges x 512 cols, 8 waves; wave wv owns wcols [wv*64, wv*64+64).
// Weight fragments are pipelined through static 2-deep register rings.
// OCCUPANCY PIN: LDS (70.9 KB) caps this kernel at 2 blocks/CU = 4 waves/SIMD.
// waves_per_eu(4,4) pins the allocator to that tier (128-VGPR budget) — with
// launch_bounds(512,4) alone it targeted 8 waves/SIMD (64 VGPR) and spilled
// the rings to scratch (r12: WRITE_SIZE 43->160 MB, k_edge 246->277 us).
__global__ __launch_bounds__(512)
__attribute__((amdgpu_waves_per_eu(4, 4))) void k_edge(
    const int* ei, const int* toj, const int* batch, const int* atype,
    const unsigned short* w0t, const unsigned short* w1t,
    const float* scb1, const float* scW2, const float* scb2, float* ws) {
  __shared__ __align__(16) char s_hh_b[64 * TSTRIDE];  // 66560 B
  __shared__ float s_dvec[TE][3];
  __shared__ float s_dist[TE], s_gtd[TE];
  __shared__ int s_tj[TE], s_ti[TE];
  __shared__ float s_wsum[8][TE];             // 2 KB

  char* s_ef_b = s_hh_b;                           // tiles 0..15
  float* s_rbfw2 = (float*)(s_hh_b + 16640);       // [16][128] f32 (8 KB)
  float* s_cvec  = (float*)(s_hh_b + 24832);       // [128] f32 (512 B)
  float* s_rbfE  = (float*)(s_hh_b + 25344);       // [64][16] f32 (4 KB)

  const int t = threadIdx.x;
  const int e0 = blockIdx.x * TE;
  const int b0 = batch[ei[e0]];

  const int lane = t & 63;
  const int wv = t >> 6;        // 0..7
  const int el = lane & 15;     // edge-in-tile (D col / B-frag edge)
  const int q  = lane >> 4;     // k-octet group

  // ---- Phase A: stage rbfW2+cvec to LDS; per-edge geometry + rbf (t<64)
  {
    const float4* src = (const float4*)(ws + WS_RBFW2);  // 512 float4
    float4* dst = (float4*)s_rbfw2;
    dst[t] = src[t];
    if (t < 32) ((float4*)s_cvec)[t] = ((const float4*)(ws + WS_CVEC))[t];
  }
  if (t < TE) {
    int e = e0 + t;
    int jn = ei[e], iN = ei[Ee + e];
    int b = batch[jn];
    float tx = (float)toj[e * 3], ty = (float)toj[e * 3 + 1], tz = (float)toj[e * 3 + 2];
    const float* L = ws + WS_L + b * 9;
    float dv[3], gv[3];
#pragma unroll
    for (int j = 0; j < 3; ++j) {
      float off = tx * L[j] + ty * L[3 + j] + tz * L[6 + j];
      dv[j] = ws[WS_PERT + iN * 3 + j] - ws[WS_PERT + jn * 3 + j] - off;
      gv[j] = ws[WS_ALIGN + iN * 3 + j] - ws[WS_ALIGN + jn * 3 + j] - off;
    }
    float dist = sqrtf(dv[0] * dv[0] + dv[1] * dv[1] + dv[2] * dv[2]);
    float gtd = sqrtf(gv[0] * gv[0] + gv[1] * gv[1] + gv[2] * gv[2]);
#pragma unroll
    for (int j = 0; j < 3; ++j) s_dvec[t][j] = dv[j];
    s_dist[t] = dist;
    s_gtd[t] = gtd;
    s_tj[t] = atype[jn]; s_ti[t] = atype[iN];
    const float step = 7.0f / 15.0f;
#pragma unroll
    for (int k = 0; k < NRBF; ++k) {
      float d = dist - (float)k * step;
      s_rbfE[t * NRBF + k] = __expf(-10.f * d * d);
    }
  }
  __syncthreads();

  // ---- Phase B: ef = silu(hb[tj]+hb[ti]+rbf@rbfW2+cvec) -> s_efT (B-frag tiles)
  {
    int e = t >> 3;              // 0..63 (edge in tile)
    int c0 = (t & 7) * 16;       // 16 hid cols per thread
    int tj = s_tj[e], ti = s_ti[e];
    float4 rb4[4];
#pragma unroll
    for (int qq = 0; qq < 4; ++qq) rb4[qq] = ((const float4*)(s_rbfE + e * NRBF))[qq];
    float rb[NRBF] = {rb4[0].x, rb4[0].y, rb4[0].z, rb4[0].w,
                      rb4[1].x, rb4[1].y, rb4[1].z, rb4[1].w,
                      rb4[2].x, rb4[2].y, rb4[2].z, rb4[2].w,
                      rb4[3].x, rb4[3].y, rb4[3].z, rb4[3].w};
    float4 z4[4];
#pragma unroll
    for (int qq = 0; qq < 4; ++qq) {
      float4 a = *(const float4*)(ws + WS_HB + tj * HID + c0 + qq * 4);
      float4 bq = *(const float4*)(ws + WS_HB + ti * HID + c0 + qq * 4);
      float4 cv = ((const float4*)s_cvec)[c0 / 4 + qq];
      z4[qq].x = a.x + bq.x + cv.x; z4[qq].y = a.y + bq.y + cv.y;
      z4[qq].z = a.z + bq.z + cv.z; z4[qq].w = a.w + bq.w + cv.w;
    }
#pragma unroll
    for (int k = 0; k < NRBF; ++k) {
      float rbk = rb[k];
#pragma unroll
      for (int qq = 0; qq < 4; ++qq) {
        float4 wv4 = ((const float4*)s_rbfw2)[k * 32 + c0 / 4 + qq];
        z4[qq].x += rbk * wv4.x; z4[qq].y += rbk * wv4.y;
        z4[qq].z += rbk * wv4.z; z4[qq].w += rbk * wv4.w;
      }
    }
    float sv[16];
#pragma unroll
    for (int qq = 0; qq < 4; ++qq) {
      sv[qq * 4 + 0] = z4[qq].x * fastrcp(1.f + __expf(-z4[qq].x));
      sv[qq * 4 + 1] = z4[qq].y * fastrcp(1.f + __expf(-z4[qq].y));
      sv[qq * 4 + 2] = z4[qq].z * fastrcp(1.f + __expf(-z4[qq].z));
      sv[qq * 4 + 3] = z4[qq].w * fastrcp(1.f + __expf(-z4[qq].w));
    }
    unsigned int w[8];
#pragma unroll
    for (int p = 0; p < 8; ++p) w[p] = pk2bf(sv[2 * p], sv[2 * p + 1]);
    // Two 16B stores, one per hid-octet o: hid = c0 + 8o .. c0 + 8o + 7
    int eT = e >> 4, elw = e & 15;
#pragma unroll
    for (int o = 0; o < 2; ++o) {
      int hid = c0 + 8 * o;
      int kt = hid >> 5;
      int oct = (hid & 31) >> 3;
      int addr = (kt * 4 + eT) * TSTRIDE + (elw + 16 * oct) * 16;
      uint4 val = {w[4 * o + 0], w[4 * o + 1], w[4 * o + 2], w[4 * o + 3]};
      *(uint4*)(s_ef_b + addr) = val;
    }
  }

  // T14 issue-early: W0 kt=0,1 fragments before the B->C barrier
  const unsigned short* w0base = w0t + (size_t)(wv * 4) * 4 * 512 + lane * 8;
  bf16x8 cawA[4], cawB[4];
#pragma unroll
  for (int m = 0; m < 4; ++m) {
    cawA[m] = *(const bf16x8*)(w0base + (size_t)(m * 4 + 0) * 512);
    cawB[m] = *(const bf16x8*)(w0base + (size_t)(m * 4 + 1) * 512);
  }
  __syncthreads();

  const unsigned short* w1base = w1t + (size_t)(wv * 4) * 16 * 512 + lane * 8;
  bf16x8 dawA[4], dawB[4];

  // ---- Phase C: GEMM1^T  hh^T = relu(W0a^T @ ef^T + latp), -> s_hhT (B-frag tiles)
  {
    f32x4 acc[4][4];  // [m = wcolTile][n = edgeTile]
#pragma unroll
    for (int m = 0; m < 4; ++m)
#pragma unroll
      for (int n = 0; n < 4; ++n) acc[m][n] = (f32x4){0.f, 0.f, 0.f, 0.f};

#define C_STEP(KT, CUR)                                                          \
  {                                                                              \
    bf16x8 bfv[4];                                                               \
    _Pragma("unroll") for (int n = 0; n < 4; ++n)                                \
        bfv[n] = *(const bf16x8*)(s_ef_b + ((KT) * 4 + n) * TSTRIDE + lane * 16);\
    __builtin_amdgcn_s_setprio(1);                                               \
    _Pragma("unroll") for (int n = 0; n < 4; ++n)                                \
        _Pragma("unroll") for (int m = 0; m < 4; ++m)                            \
            acc[m][n] = __builtin_amdgcn_mfma_f32_16x16x32_bf16(                 \
                CUR[m], bfv[n], acc[m][n], 0, 0, 0);                             \
    __builtin_amdgcn_s_setprio(0);                                               \
    if ((KT) + 2 < 4) {                                                          \
      _Pragma("unroll") for (int m = 0; m < 4; ++m)                              \
          CUR[m] = *(const bf16x8*)(w0base + (size_t)(m * 4 + (KT) + 2) * 512);  \
    }                                                                            \
  }
    C_STEP(0, cawA)
    C_STEP(1, cawB)
    C_STEP(2, cawA)
    C_STEP(3, cawB)
#undef C_STEP

    __syncthreads();   // ALL s_efT reads complete before s_hhT overwrites the alias
    // Epilogue: lane holds D[wcol = m*16 + q*4 + r][edge = n*16 + el].
    // Write as GEMM2 B-frag: kTile = wcol>>5, lane' = el + 16*((wcol&31)>>3).
#pragma unroll
    for (int m = 0; m < 4; ++m) {
      float4 lp = *(const float4*)(ws + WS_LATP + b0 * FCH + wv * 64 + m * 16 + q * 4);
#pragma unroll
      for (int n = 0; n < 4; ++n) {
        f32x4 v = acc[m][n];
        float h0 = fmaxf(v[0] + lp.x, 0.f);
        float h1 = fmaxf(v[1] + lp.y, 0.f);
        float h2 = fmaxf(v[2] + lp.z, 0.f);
        float h3 = fmaxf(v[3] + lp.w, 0.f);
        uint2 val = {pk2bf(h0, h1), pk2bf(h2, h3)};
        int kT = wv * 2 + (m >> 1);
        int oct = (m & 1) * 2 + (q >> 1);
        int addr = (kT * 4 + n) * TSTRIDE + (el + 16 * oct) * 16 + (q & 1) * 8;
        *(uint2*)(s_hh_b + addr) = val;
      }
    }
  }

  // T14 issue-early: W1 kt=0,1 fragments before the C->D barrier
#pragma unroll
  for (int m = 0; m < 4; ++m) {
    dawA[m] = *(const bf16x8*)(w1base + (size_t)(m * 16 + 0) * 512);
    dawB[m] = *(const bf16x8*)(w1base + (size_t)(m * 16 + 1) * 512);
  }
  __syncthreads();

  // ---- Phase D: GEMM2^T + fused score reduction (2-deep weight ring)
  {
    f32x4 acc[4][4];  // [m = w1colTile][n = edgeTile]
#pragma unroll
    for (int m = 0; m < 4; ++m)
#pragma unroll
      for (int n = 0; n < 4; ++n) acc[m][n] = (f32x4){0.f, 0.f, 0.f, 0.f};

#define D_STEP(KT, CUR)                                                          \
  {                                                                              \
    bf16x8 bfv[4];                                                               \
    _Pragma("unroll") for (int n = 0; n < 4; ++n)                                \
        bfv[n] = *(const bf16x8*)(s_hh_b + ((KT) * 4 + n) * TSTRIDE + lane * 16);\
    __builtin_amdgcn_s_setprio(1);                                               \
    _Pragma("unroll") for (int n = 0; n < 4; ++n)                                \
        _Pragma("unroll") for (int m = 0; m < 4; ++m)                            \
            acc[m][n] = __builtin_amdgcn_mfma_f32_16x16x32_bf16(                 \
                CUR[m], bfv[n], acc[m][n], 0, 0, 0);                             \
    __builtin_amdgcn_s_setprio(0);                                               \
    if ((KT) + 2 < 16) {                                                         \
      _Pragma("unroll") for (int m = 0; m < 4; ++m)                              \
          CUR[m] = *(const bf16x8*)(w1base + (size_t)(m * 16 + (KT) + 2) * 512); \
    }                                                                            \
  }
    D_STEP(0, dawA)  D_STEP(1, dawB)
    D_STEP(2, dawA)  D_STEP(3, dawB)
    D_STEP(4, dawA)  D_STEP(5, dawB)
    D_STEP(6, dawA)  D_STEP(7, dawB)
    D_STEP(8, dawA)  D_STEP(9, dawB)
    D_STEP(10, dawA) D_STEP(11, dawB)
    D_STEP(12, dawA) D_STEP(13, dawB)
    D_STEP(14, dawA) D_STEP(15, dawB)
#undef D_STEP

    // hh1 = relu(acc + b1); p[edge] += hh1 * W2, reduced over w1cols
    float p[4] = {0.f, 0.f, 0.f, 0.f};   // per edgeTile n
#pragma unroll
    for (int m = 0; m < 4; ++m) {
      int colb = wv * 64 + m * 16 + q * 4;
      float4 b1v = *(const float4*)(scb1 + colb);
      float4 w2v = *(const float4*)(scW2 + colb);
#pragma unroll
      for (int n = 0; n < 4; ++n) {
        f32x4 v = acc[m][n];
        p[n] += fmaxf(v[0] + b1v.x, 0.f) * w2v.x;
        p[n] += fmaxf(v[1] + b1v.y, 0.f) * w2v.y;
        p[n] += fmaxf(v[2] + b1v.z, 0.f) * w2v.z;
        p[n] += fmaxf(v[3] + b1v.w, 0.f) * w2v.w;
      }
    }
    // reduce over q (lane bits 4..5)
#pragma unroll
    for (int n = 0; n < 4; ++n) {
      float x = p[n];
      x += __shfl_xor(x, 16);
      x += __shfl_xor(x, 32);
      p[n] = x;
    }
    if (lane < 16) {
#pragma unroll
      for (int n = 0; n < 4; ++n) s_wsum[wv][n * 16 + el] = p[n];
    }
  }
  __syncthreads();

  // ---- Phase E: segment-mean scatter (threads 0..63)
  if (t < TE) {
    int e = e0 + t;
    float score = scb2[0];
#pragma unroll
    for (int w = 0; w < 8; ++w) score += s_wsum[w][t];
    int jn = ei[e], iN = ei[Ee + e];
    int s = e;
    while (s > 0 && ei[s - 1] == jn && ei[Ee + s - 1] == iN) --s;
    int en = e;
    while (en + 1 < Ee && ei[en + 1] == jn && ei[Ee + en + 1] == iN) ++en;
    float invc = fastrcp((float)(en - s + 1));
    float dist = s_dist[t];
    float rden = fastrcp(dist + 1e-8f);
    float gts = s_gtd[t] - dist;
#pragma unroll
    for (int j = 0; j < 3; ++j) {
      float dir = s_dvec[t][j] * rden;
      atomicAdd(&ws[WS_SN + iN * 3 + j], score * dir * invc);
      atomicAdd(&ws[WS_GN + iN * 3 + j], gts * dir * invc);
    }
  }
}

// ---------------- per-node: loss terms, preds, center sums ----------------
__global__ void k_node2(const int* batch, float* ws) {
  int n = blockIdx.x * blockDim.x + threadIdx.x;
  if (n >= Nn) return;
  int b = batch[n];
  float sig = ws[WS_SIG + b];
#pragma unroll
  for (int j = 0; j < 3; ++j) {
    float s = ws[WS_SN + n * 3 + j], g = ws[WS_GN + n * 3 + j];
    float d = s - g / sig;
    atomicAdd(&ws[WS_BSUM + b * 3 + j], d * d);
    float pr = ws[WS_PERT + n * 3 + j] + s / sig;
    ws[WS_PREDS + n * 3 + j] = pr;
    atomicAdd(&ws[WS_CENTER + b * 3 + j], pr);
  }
}

// ---------------- per-node: global min/max of dc ----------------
__global__ void k_minmax(const int* batch, const int* num_atoms, float* ws) {
  int n = blockIdx.x * blockDim.x + threadIdx.x;
  int lane = threadIdx.x & 63, wid = threadIdx.x >> 6;
  float mx[3], mn[3];
  if (n < Nn) {
    int b = batch[n];
    float na = (float)num_atoms[b];
#pragma unroll
    for (int j = 0; j < 3; ++j) {
      float v = ws[WS_PREDS + n * 3 + j] - ws[WS_CENTER + b * 3 + j] / na;
      mx[j] = v; mn[j] = v;
    }
  } else {
#pragma unroll
    for (int j = 0; j < 3; ++j) { mx[j] = -3.0e38f; mn[j] = 3.0e38f; }
  }
#pragma unroll
  for (int off = 32; off >= 1; off >>= 1) {
#pragma unroll
    for (int j = 0; j < 3; ++j) {
      mx[j] = fmaxf(mx[j], __shfl_xor(mx[j], off));
      mn[j] = fminf(mn[j], __shfl_xor(mn[j], off));
    }
  }
  __shared__ float smx[4][3], smn[4][3];
  if (lane == 0) {
#pragma unroll
    for (int j = 0; j < 3; ++j) { smx[wid][j] = mx[j]; smn[wid][j] = mn[j]; }
  }
  __syncthreads();
  if (threadIdx.x == 0) {
#pragma unroll
    for (int j = 0; j < 3; ++j) {
      float M = fmaxf(fmaxf(smx[0][j], smx[1][j]), fmaxf(smx[2][j], smx[3][j]));
      float m = fminf(fminf(smn[0][j], smn[1][j]), fminf(smn[2][j], smn[3][j]));
      atomicMaxFloat(&ws[WS_MINMAX + j], M);
      atomicMinFloat(&ws[WS_MINMAX + 3 + j], m);
    }
  }
}

// ---------------- finalize (parallel over batches) ----------------
__global__ void k_final(const int* num_atoms, const float* ws, float* out) {
  int t = threadIdx.x;  // 128 threads
  float loss = 0.f;
  if (t < Bb) {
    float na = (float)num_atoms[t];
    loss = (ws[WS_BSUM + t * 3] + ws[WS_BSUM + t * 3 + 1] + ws[WS_BSUM + t * 3 + 2]) / na;
  }
#pragma unroll
  for (int off = 32; off >= 1; off >>= 1) loss += __shfl_xor(loss, off);
  __shared__ float s2[2];
  if ((t & 63) == 0) s2[t >> 6] = loss;
  __syncthreads();
  if (t == 0) {
    float L = (s2[0] + s2[1]) / (3.0f * (float)Bb);
    float pbs = fabsf(ws[WS_MINMAX + 0] + ws[WS_MINMAX + 3]) +
                fabsf(ws[WS_MINMAX + 1] + ws[WS_MINMAX + 4]) +
                fabsf(ws[WS_MINMAX + 2] + ws[WS_MINMAX + 5]);
    out[0] = L;
    out[1] = pbs;
  }
}

extern "C" void kernel_launch(void* const* d_in, const int* in_sizes, int n_in,
                              void* d_out, int out_size, void* d_ws, size_t ws_size,
                              hipStream_t stream) {
  const float* latents = (const float*)d_in[0];
  const float* gtf     = (const float*)d_in[1];
  const float* lengths = (const float*)d_in[2];
  const float* angles  = (const float*)d_in[3];
  const float* noise   = (const float*)d_in[4];
  const float* sigmas  = (const float*)d_in[5];
  const float* aemb    = (const float*)d_in[6];
  const float* rbfW    = (const float*)d_in[7];
  const float* rbfb    = (const float*)d_in[8];
  const float* bbW     = (const float*)d_in[9];
  const float* bbb     = (const float*)d_in[10];
  const float* scW0    = (const float*)d_in[11];
  const float* scb0    = (const float*)d_in[12];
  const float* scW1    = (const float*)d_in[13];
  const float* scb1    = (const float*)d_in[14];
  const float* scW2    = (const float*)d_in[15];
  const float* scb2    = (const float*)d_in[16];
  const int* num_atoms = (const int*)d_in[17];
  const int* atype     = (const int*)d_in[18];
  const int* batch     = (const int*)d_in[19];
  const int* ei        = (const int*)d_in[20];
  const int* toj       = (const int*)d_in[21];
  const int* tsteps    = (const int*)d_in[22];
  float* ws = (float*)d_ws;
  float* out = (float*)d_out;
  unsigned short* w0t = (unsigned short*)(ws + WS_W0T_F);
  unsigned short* w1t = (unsigned short*)(ws + WS_W1T_F);

  hipLaunchKernelGGL(k_pre, dim3(744), dim3(256), 0, stream,
                     lengths, angles, sigmas, tsteps, aemb, bbW, rbfW, rbfb, bbb,
                     latents, scW0, scb0, scW1, gtf, noise, batch, atype, w0t, w1t, ws);
  hipLaunchKernelGGL(k_edge, dim3(Ee / TE), dim3(512), 0, stream,
                     ei, toj, batch, atype, w0t, w1t, scb1, scW2, scb2, ws);
  hipLaunchKernelGGL(k_node2, dim3(50), dim3(256), 0, stream, batch, ws);
  hipLaunchKernelGGL(k_minmax, dim3(50), dim3(256), 0, stream, batch, num_atoms, ws);
  hipLaunchKernelGGL(k_final, dim3(1), dim3(128), 0, stream, num_atoms, ws, out);
}

// Round 14
// 315.314 us; speedup vs baseline: 1.1162x; 1.1162x over previous
//
#include <hip/hip_runtime.h>
#include <hip/hip_bf16.h>

// ---------------- problem constants ----------------
namespace {
constexpr int Bb = 128, Nn = 12800, Ee = 262144;
constexpr int LAT = 256, HID = 128, FCH = 512, NRBF = 16;
constexpr int TE = 64;        // edges per block (divides 2048 = edges/graph)
constexpr int TSTRIDE = 1040; // activation-tile stride in bytes

// workspace offsets (floats)
constexpr int WS_L      = 0;        // B*9
constexpr int WS_LI     = 1152;     // B*9
constexpr int WS_SIG    = 2304;     // B
constexpr int WS_RBFW2  = 2432;     // 16*128
constexpr int WS_CVEC   = 4480;     // 128
constexpr int WS_HB     = 4608;     // 100*128
constexpr int WS_LATP   = 17408;    // B*512
constexpr int WS_PERT   = 82944;    // N*3
constexpr int WS_ALIGN  = 121344;   // N*3
constexpr int WS_SN     = 159744;   // N*3 (atomic)
constexpr int WS_GN     = 198144;   // N*3 (atomic)
constexpr int WS_PREDS  = 236544;   // N*3
constexpr int WS_BSUM   = 274944;   // B*3 (atomic)
constexpr int WS_CENTER = 275328;   // B*3 (atomic)
constexpr int WS_MINMAX = 275712;   // 6   (max x3, min x3)
// bf16 fragment-tiled weights (stored as ushort), float-index base:
constexpr int WS_W0T_F   = 276000;  // ushort[512*128]  (= 32768 floats)
constexpr int WS_W1T_F   = 308768;  // ushort[512*512]  (= 131072 floats)
constexpr int WS_RBFW2T_F = 439840; // ushort[8 tiles * 64 lanes * 8] (= 2048 floats)
}

typedef short bf16x8 __attribute__((ext_vector_type(8)));
typedef unsigned short u16x8 __attribute__((ext_vector_type(8)));
typedef float f32x4 __attribute__((ext_vector_type(4)));

static __device__ __forceinline__ unsigned short f2bf(float f) {
  unsigned int u = __float_as_uint(f);
  unsigned int r = (u + 0x7fffu + ((u >> 16) & 1u)) >> 16;
  return (unsigned short)r;
}
// single-instruction packed f32->bf16 pair: low16 = bf16(a), high16 = bf16(b)
static __device__ __forceinline__ unsigned int pk2bf(float a, float b) {
  unsigned int r;
  asm("v_cvt_pk_bf16_f32 %0, %1, %2" : "=v"(r) : "v"(a), "v"(b));
  return r;
}
static __device__ __forceinline__ float fastrcp(float x) {
  return __builtin_amdgcn_rcpf(x);
}

static __device__ __forceinline__ void make_lattice(
    const float* lengths, const float* angles, int b, float L[9], float Li[9]) {
  float a = lengths[b * 3 + 0], bl = lengths[b * 3 + 1], c = lengths[b * 3 + 2];
  const float d2r = 0.017453292519943295f;
  float al = angles[b * 3 + 0] * d2r, be = angles[b * 3 + 1] * d2r, ga = angles[b * 3 + 2] * d2r;
  float ca = cosf(al), cb = cosf(be), cg = cosf(ga), sa = sinf(al), sb = sinf(be);
  float val = (ca * cb - cg) / (sa * sb);
  val = fminf(1.f, fmaxf(-1.f, val));
  float gs = acosf(val);
  L[0] = a * sb;              L[1] = 0.f;                L[2] = a * cb;
  L[3] = -bl * sa * cosf(gs); L[4] = bl * sa * sinf(gs); L[5] = bl * ca;
  L[6] = 0.f;                 L[7] = 0.f;                L[8] = c;
  float det = L[0] * (L[4] * L[8] - L[5] * L[7])
            - L[1] * (L[3] * L[8] - L[5] * L[6])
            + L[2] * (L[3] * L[7] - L[4] * L[6]);
  float id = 1.f / det;
  Li[0] =  (L[4] * L[8] - L[5] * L[7]) * id;
  Li[1] = -(L[1] * L[8] - L[2] * L[7]) * id;
  Li[2] =  (L[1] * L[5] - L[2] * L[4]) * id;
  Li[3] = -(L[3] * L[8] - L[5] * L[6]) * id;
  Li[4] =  (L[0] * L[8] - L[2] * L[6]) * id;
  Li[5] = -(L[0] * L[5] - L[2] * L[3]) * id;
  Li[6] =  (L[3] * L[7] - L[4] * L[6]) * id;
  Li[7] = -(L[0] * L[7] - L[1] * L[6]) * id;
  Li[8] =  (L[0] * L[4] - L[1] * L[3]) * id;
}

static __device__ __forceinline__ void atomicMaxFloat(float* addr, float val) {
  int* ai = reinterpret_cast<int*>(addr);
  int old = *ai;
  while (__int_as_float(old) < val) {
    int assumed = old;
    old = atomicCAS(ai, assumed, __float_as_int(val));
    if (old == assumed) break;
  }
}
static __device__ __forceinline__ void atomicMinFloat(float* addr, float val) {
  int* ai = reinterpret_cast<int*>(addr);
  int old = *ai;
  while (__int_as_float(old) > val) {
    int assumed = old;
    old = atomicCAS(ai, assumed, __float_as_int(val));
    if (old == assumed) break;
  }
}

// ---------------- fused prologue: all mutually-independent prep work ----------------
// blocks   0..303 : zero accumulators, init MINMAX
// block      304  : lattice + sigma -> ws
// blocks 305..404 : hb = atom_emb @ bb_W
// block      405  : rbfW2 / cvec (cvec still consumed by k_edge)
// blocks 406..533 : lat_proj
// blocks 534..565 : cvtW0 (coalesced 16B writes)
// blocks 566..693 : cvtW1 (coalesced 16B writes)
// blocks 694..695 : rbfw2t A-frag tiles (recomputed directly; K padded 16->32)
// blocks 696..745 : per-node geometry (lattice recomputed inline per node)
__global__ __launch_bounds__(256) void k_pre(
    const float* lengths, const float* angles, const float* sigmas, const int* tsteps,
    const float* aemb, const float* bbW, const float* rbfW, const float* rbfb,
    const float* bbb, const float* latents, const float* scW0, const float* scb0,
    const float* scW1, const float* gtf, const float* noise, const int* batch,
    const int* atype, unsigned short* w0t, unsigned short* w1t,
    unsigned short* rbfw2t, float* ws) {
  const int blk = blockIdx.x, t = threadIdx.x;
  if (blk < 304) {
    int gid = blk * 256 + t;
    if (gid < 2 * Nn * 3) ws[WS_SN + gid] = 0.f;
    else if (gid < 2 * Nn * 3 + 2 * Bb * 3) ws[WS_BSUM + (gid - 2 * Nn * 3)] = 0.f;
    else if (gid < 2 * Nn * 3 + 2 * Bb * 3 + 3) ws[WS_MINMAX + (gid - 2 * Nn * 3 - 2 * Bb * 3)] = -3.0e38f;
    else if (gid < 2 * Nn * 3 + 2 * Bb * 3 + 6) ws[WS_MINMAX + (gid - 2 * Nn * 3 - 2 * Bb * 3)] = 3.0e38f;
  } else if (blk == 304) {
    int b = t;
    if (b >= Bb) return;
    float L[9], Li[9];
    make_lattice(lengths, angles, b, L, Li);
#pragma unroll
    for (int i = 0; i < 9; ++i) {
      ws[WS_L + b * 9 + i] = L[i];
      ws[WS_LI + b * 9 + i] = Li[i];
    }
    ws[WS_SIG + b] = sigmas[tsteps[b]];
  } else if (blk < 405) {
    int tile = blk - 305;
    if (t < HID) {
      float acc = 0.f;
      for (int k = 0; k < HID; ++k) acc += aemb[tile * HID + k] * bbW[k * HID + t];
      ws[WS_HB + tile * HID + t] = acc;
    }
  } else if (blk == 405) {
    if (t < HID) {
      float accs[NRBF];
#pragma unroll
      for (int k = 0; k < NRBF; ++k) accs[k] = 0.f;
      float accb = 0.f;
      for (int m = 0; m < HID; ++m) {
        float w = bbW[m * HID + t];
#pragma unroll
        for (int k = 0; k < NRBF; ++k) accs[k] += rbfW[k * HID + m] * w;
        accb += rbfb[m] * w;
      }
#pragma unroll
      for (int k = 0; k < NRBF; ++k) ws[WS_RBFW2 + k * HID + t] = accs[k];
      ws[WS_CVEC + t] = accb + bbb[t];
    }
  } else if (blk < 534) {
    int b = blk - 406;
    __shared__ float lat[LAT];
    lat[t] = latents[b * LAT + t];
    __syncthreads();
    int c0 = 2 * t;
    float a0 = 0.f, a1 = 0.f;
    for (int m = 0; m < LAT; ++m) {
      float2 w = *reinterpret_cast<const float2*>(scW0 + (HID + m) * FCH + c0);
      float lm = lat[m];
      a0 += lm * w.x;
      a1 += lm * w.y;
    }
    ws[WS_LATP + b * FCH + c0] = a0 + scb0[c0];
    ws[WS_LATP + b * FCH + c0 + 1] = a1 + scb0[c0 + 1];
  } else if (blk < 566) {
    // cvtW0: thread id8 produces w0t[id8*8 .. id8*8+7] (one coalesced 16B store)
    int id8 = (blk - 534) * 256 + t;     // 0..8191
    int tile = id8 >> 6, lf = id8 & 63;  // tile = colTile*4 + kTile
    int colTile = tile >> 2, kTile = tile & 3;
    int col = colTile * 16 + (lf & 15);
    int kbase = kTile * 32 + (lf >> 4) * 8;
    u16x8 v;
#pragma unroll
    for (int e = 0; e < 8; ++e) v[e] = f2bf(scW0[(kbase + e) * FCH + col]);
    *(u16x8*)(w0t + id8 * 8) = v;
  } else if (blk < 694) {
    // cvtW1: thread id8 produces w1t[id8*8 .. id8*8+7]
    int id8 = (blk - 566) * 256 + t;     // 0..32767
    int tile = id8 >> 6, lf = id8 & 63;  // tile = colTile*16 + kTile
    int colTile = tile >> 4, kTile = tile & 15;
    int col = colTile * 16 + (lf & 15);
    int kbase = kTile * 32 + (lf >> 4) * 8;
    u16x8 v;
#pragma unroll
    for (int e = 0; e < 8; ++e) v[e] = f2bf(scW1[(kbase + e) * FCH + col]);
    *(u16x8*)(w1t + id8 * 8) = v;
  } else if (blk < 696) {
    // rbfw2t: A-frag tiles of rbfW2^T (8 colTiles x 1 kTile, K padded 16->32).
    // A-frag lane lf holds A[colTile*16+(lf&15)][k = 8*(lf>>4)+e], A[c][k] = rbfw2[k][c].
    // rbfw2 recomputed directly (avoids intra-launch dependency on block 405).
    int id = (blk - 694) * 256 + t;      // 0..511
    if (id < 512) {
      int tile = id >> 6, lf = id & 63;  // tile = colTile 0..7
      int c = tile * 16 + (lf & 15);
      u16x8 v;
#pragma unroll
      for (int e = 0; e < 8; ++e) {
        int k = (lf >> 4) * 8 + e;
        if (k < NRBF) {
          float acc = 0.f;
          for (int m = 0; m < HID; ++m) acc += rbfW[k * HID + m] * bbW[m * HID + c];
          v[e] = f2bf(acc);
        } else {
          v[e] = 0;
        }
      }
      *(u16x8*)(rbfw2t + id * 8) = v;
    }
  } else {
    // per-node geometry, lattice recomputed inline
    int n = (blk - 696) * 256 + t;
    if (n >= Nn) return;
    int b = batch[n];
    float L[9], Li[9];
    make_lattice(lengths, angles, b, L, Li);
    float sig = sigmas[tsteps[b]];
    float f0 = gtf[n * 3], f1 = gtf[n * 3 + 1], f2 = gtf[n * 3 + 2];
    float cg[3], p0[3], fp[3], pe[3], fg[3], fd[3];
#pragma unroll
    for (int j = 0; j < 3; ++j) cg[j] = f0 * L[j] + f1 * L[3 + j] + f2 * L[6 + j];
#pragma unroll
    for (int j = 0; j < 3; ++j) p0[j] = cg[j] + sig * noise[n * 3 + j];
#pragma unroll
    for (int j = 0; j < 3; ++j) {
      float v = p0[0] * Li[j] + p0[1] * Li[3 + j] + p0[2] * Li[6 + j];
      fp[j] = v - floorf(v);
    }
#pragma unroll
    for (int j = 0; j < 3; ++j) pe[j] = fp[0] * L[j] + fp[1] * L[3 + j] + fp[2] * L[6 + j];
#pragma unroll
    for (int j = 0; j < 3; ++j) fg[j] = cg[0] * Li[j] + cg[1] * Li[3 + j] + cg[2] * Li[6 + j];
#pragma unroll
    for (int j = 0; j < 3; ++j) { float d = fg[j] - fp[j]; fd[j] = d - rintf(d); }
#pragma unroll
    for (int j = 0; j < 3; ++j) {
      ws[WS_PERT + n * 3 + j] = pe[j];
      ws[WS_ALIGN + n * 3 + j] = pe[j] + fd[0] * L[j] + fd[1] * L[3 + j] + fd[2] * L[6 + j];
    }
  }
}

// ---------------- the big fused MFMA edge kernel (transposed compute) ----------------
// D[wcol][edge] = mfma(A = W^T fragment, B = act^T fragment); weight tiles in
// ws are direct A-fragments. Activations in LDS in B-fragment tile order at
// TSTRIDE-byte tile stride. Every ds_read is lane*16B contiguous.
// Tile: 64 edges x 512 cols, 8 waves; wave wv owns wcols [wv*64, wv*64+64).
// Phase B is MFMA-ized: ef_pre = rbf @ rbfW2 via 4 MFMAs/wave (A = rbfw2t
// fragments, B = per-edge rbf built in-register); epilogue adds hb/cvec,
// silu, packs straight into GEMM1's B-frag LDS layout.
// r11 structure otherwise (per-kt weight loads — no rings: the allocator
// pins 64 VGPR at 512 threads and spills anything deeper; r12/r13 evidence).
// LDS ~70 KB -> 2 blocks/CU.
__global__ __launch_bounds__(512, 4) void k_edge(
    const int* ei, const int* toj, const int* batch, const int* atype,
    const unsigned short* w0t, const unsigned short* w1t,
    const unsigned short* rbfw2t,
    const float* scb1, const float* scW2, const float* scb2, float* ws) {
  __shared__ __align__(16) char s_hh_b[64 * TSTRIDE];  // 66560 B
  __shared__ float s_dvec[TE][3];
  __shared__ float s_dist[TE], s_gtd[TE];
  __shared__ int s_tj[TE], s_ti[TE];
  __shared__ float s_wsum[8][TE];             // 2 KB

  char* s_ef_b = s_hh_b;                      // tiles 0..15

  const int t = threadIdx.x;
  const int e0 = blockIdx.x * TE;
  const int b0 = batch[ei[e0]];

  const int lane = t & 63;
  const int wv = t >> 6;        // 0..7
  const int el = lane & 15;     // edge-in-tile (D col / B-frag edge)
  const int q  = lane >> 4;     // k-octet group

  // ---- Phase A: per-edge geometry (t<64)
  if (t < TE) {
    int e = e0 + t;
    int jn = ei[e], iN = ei[Ee + e];
    int b = batch[jn];
    float tx = (float)toj[e * 3], ty = (float)toj[e * 3 + 1], tz = (float)toj[e * 3 + 2];
    const float* L = ws + WS_L + b * 9;
    float dv[3], gv[3];
#pragma unroll
    for (int j = 0; j < 3; ++j) {
      float off = tx * L[j] + ty * L[3 + j] + tz * L[6 + j];
      dv[j] = ws[WS_PERT + iN * 3 + j] - ws[WS_PERT + jn * 3 + j] - off;
      gv[j] = ws[WS_ALIGN + iN * 3 + j] - ws[WS_ALIGN + jn * 3 + j] - off;
    }
    float dist = sqrtf(dv[0] * dv[0] + dv[1] * dv[1] + dv[2] * dv[2]);
    float gtd = sqrtf(gv[0] * gv[0] + gv[1] * gv[1] + gv[2] * gv[2]);
#pragma unroll
    for (int j = 0; j < 3; ++j) s_dvec[t][j] = dv[j];
    s_dist[t] = dist;
    s_gtd[t] = gtd;
    s_tj[t] = atype[jn]; s_ti[t] = atype[iN];
  }
  __syncthreads();

  // ---- Phase B (MFMA): ef = silu(rbf@rbfW2 + hb[tj] + hb[ti] + cvec) -> s_efT
  // Wave wv owns hid colTile ct = wv (cols wv*16 .. wv*16+15) x 4 edgeTiles.
  {
    bf16x8 arb = *(const bf16x8*)(rbfw2t + wv * 512 + lane * 8);
    const float step = 7.0f / 15.0f;
    bf16x8 brb[4];
#pragma unroll
    for (int n = 0; n < 4; ++n) {
      float d = s_dist[n * 16 + el];
      unsigned int wb0 = 0, wb1 = 0, wb2 = 0, wb3 = 0;
      if (q < 2) {
        float kbase = (float)(8 * q) * step;
        float d0 = d - kbase;
#pragma unroll
        for (int p = 0; p < 4; ++p) {
          float m0 = d0 - (float)(2 * p) * step;
          float m1 = m0 - step;
          unsigned int r = pk2bf(__expf(-10.f * m0 * m0), __expf(-10.f * m1 * m1));
          if (p == 0) wb0 = r; else if (p == 1) wb1 = r;
          else if (p == 2) wb2 = r; else wb3 = r;
        }
      }
      uint4 u = {wb0, wb1, wb2, wb3};
      brb[n] = *reinterpret_cast<bf16x8*>(&u);
    }
    f32x4 accB[4];
#pragma unroll
    for (int n = 0; n < 4; ++n)
      accB[n] = __builtin_amdgcn_mfma_f32_16x16x32_bf16(
          arb, brb[n], (f32x4){0.f, 0.f, 0.f, 0.f}, 0, 0, 0);
    // epilogue: lane holds D[col = wv*16 + q*4 + r][edge = n*16 + el]
    int col0 = wv * 16 + q * 4;
    float4 cv = *(const float4*)(ws + WS_CVEC + col0);
    int kT = wv >> 1;
    int oct = (wv & 1) * 2 + (q >> 1);
#pragma unroll
    for (int n = 0; n < 4; ++n) {
      int eg = n * 16 + el;
      int tj = s_tj[eg], ti = s_ti[eg];
      float4 hj = *(const float4*)(ws + WS_HB + tj * HID + col0);
      float4 hi = *(const float4*)(ws + WS_HB + ti * HID + col0);
      f32x4 a = accB[n];
      float z0 = a[0] + hj.x + hi.x + cv.x;
      float z1 = a[1] + hj.y + hi.y + cv.y;
      float z2 = a[2] + hj.z + hi.z + cv.z;
      float z3 = a[3] + hj.w + hi.w + cv.w;
      float s0 = z0 * fastrcp(1.f + __expf(-z0));
      float s1 = z1 * fastrcp(1.f + __expf(-z1));
      float s2 = z2 * fastrcp(1.f + __expf(-z2));
      float s3 = z3 * fastrcp(1.f + __expf(-z3));
      uint2 val = {pk2bf(s0, s1), pk2bf(s2, s3)};
      int addr = (kT * 4 + n) * TSTRIDE + (el + 16 * oct) * 16 + (q & 1) * 8;
      *(uint2*)(s_ef_b + addr) = val;
    }
  }
  __syncthreads();

  // ---- Phase C: GEMM1^T  hh^T = relu(W0a^T @ ef^T + latp) -> s_hhT (B-frag tiles)
  {
    f32x4 acc[4][4];  // [m = wcolTile][n = edgeTile]
#pragma unroll
    for (int m = 0; m < 4; ++m)
#pragma unroll
      for (int n = 0; n < 4; ++n) acc[m][n] = (f32x4){0.f, 0.f, 0.f, 0.f};
    const unsigned short* w0base = w0t + (size_t)(wv * 4) * 4 * 512 + lane * 8;
#pragma unroll
    for (int kt = 0; kt < 4; ++kt) {
      bf16x8 aw[4];
#pragma unroll
      for (int m = 0; m < 4; ++m)
        aw[m] = *(const bf16x8*)(w0base + (size_t)(m * 4 + kt) * 512);
      bf16x8 bf[4];
#pragma unroll
      for (int n = 0; n < 4; ++n)
        bf[n] = *(const bf16x8*)(s_ef_b + (kt * 4 + n) * TSTRIDE + lane * 16);
      __builtin_amdgcn_s_setprio(1);
#pragma unroll
      for (int n = 0; n < 4; ++n)
#pragma unroll
        for (int m = 0; m < 4; ++m)
          acc[m][n] = __builtin_amdgcn_mfma_f32_16x16x32_bf16(aw[m], bf[n], acc[m][n], 0, 0, 0);
      __builtin_amdgcn_s_setprio(0);
    }
    __syncthreads();   // ALL s_efT reads complete before s_hhT overwrites the alias
    // Epilogue: lane holds D[wcol = m*16 + q*4 + r][edge = n*16 + el].
#pragma unroll
    for (int m = 0; m < 4; ++m) {
      float4 lp = *(const float4*)(ws + WS_LATP + b0 * FCH + wv * 64 + m * 16 + q * 4);
#pragma unroll
      for (int n = 0; n < 4; ++n) {
        f32x4 v = acc[m][n];
        float h0 = fmaxf(v[0] + lp.x, 0.f);
        float h1 = fmaxf(v[1] + lp.y, 0.f);
        float h2 = fmaxf(v[2] + lp.z, 0.f);
        float h3 = fmaxf(v[3] + lp.w, 0.f);
        uint2 val = {pk2bf(h0, h1), pk2bf(h2, h3)};
        int kT = wv * 2 + (m >> 1);
        int oct = (m & 1) * 2 + (q >> 1);
        int addr = (kT * 4 + n) * TSTRIDE + (el + 16 * oct) * 16 + (q & 1) * 8;
        *(uint2*)(s_hh_b + addr) = val;
      }
    }
  }
  __syncthreads();

  // ---- Phase D: GEMM2^T + fused score reduction
  {
    f32x4 acc[4][4];  // [m = w1colTile][n = edgeTile]
#pragma unroll
    for (int m = 0; m < 4; ++m)
#pragma unroll
      for (int n = 0; n < 4; ++n) acc[m][n] = (f32x4){0.f, 0.f, 0.f, 0.f};
    const unsigned short* w1base = w1t + (size_t)(wv * 4) * 16 * 512 + lane * 8;
#pragma unroll 4
    for (int kt = 0; kt < 16; ++kt) {
      bf16x8 aw[4];
#pragma unroll
      for (int m = 0; m < 4; ++m)
        aw[m] = *(const bf16x8*)(w1base + (size_t)(m * 16 + kt) * 512);
      bf16x8 bf[4];
#pragma unroll
      for (int n = 0; n < 4; ++n)
        bf[n] = *(const bf16x8*)(s_hh_b + (kt * 4 + n) * TSTRIDE + lane * 16);
      __builtin_amdgcn_s_setprio(1);
#pragma unroll
      for (int n = 0; n < 4; ++n)
#pragma unroll
        for (int m = 0; m < 4; ++m)
          acc[m][n] = __builtin_amdgcn_mfma_f32_16x16x32_bf16(aw[m], bf[n], acc[m][n], 0, 0, 0);
      __builtin_amdgcn_s_setprio(0);
    }
    // hh1 = relu(acc + b1); p[edge] += hh1 * W2, reduced over w1cols
    float p[4] = {0.f, 0.f, 0.f, 0.f};   // per edgeTile n
#pragma unroll
    for (int m = 0; m < 4; ++m) {
      int colb = wv * 64 + m * 16 + q * 4;
      float4 b1v = *(const float4*)(scb1 + colb);
      float4 w2v = *(const float4*)(scW2 + colb);
#pragma unroll
      for (int n = 0; n < 4; ++n) {
        f32x4 v = acc[m][n];
        p[n] += fmaxf(v[0] + b1v.x, 0.f) * w2v.x;
        p[n] += fmaxf(v[1] + b1v.y, 0.f) * w2v.y;
        p[n] += fmaxf(v[2] + b1v.z, 0.f) * w2v.z;
        p[n] += fmaxf(v[3] + b1v.w, 0.f) * w2v.w;
      }
    }
    // reduce over q (lane bits 4..5)
#pragma unroll
    for (int n = 0; n < 4; ++n) {
      float x = p[n];
      x += __shfl_xor(x, 16);
      x += __shfl_xor(x, 32);
      p[n] = x;
    }
    if (lane < 16) {
#pragma unroll
      for (int n = 0; n < 4; ++n) s_wsum[wv][n * 16 + el] = p[n];
    }
  }
  __syncthreads();

  // ---- Phase E: segment-mean scatter (threads 0..63)
  if (t < TE) {
    int e = e0 + t;
    float score = scb2[0];
#pragma unroll
    for (int w = 0; w < 8; ++w) score += s_wsum[w][t];
    int jn = ei[e], iN = ei[Ee + e];
    int s = e;
    while (s > 0 && ei[s - 1] == jn && ei[Ee + s - 1] == iN) --s;
    int en = e;
    while (en + 1 < Ee && ei[en + 1] == jn && ei[Ee + en + 1] == iN) ++en;
    float invc = fastrcp((float)(en - s + 1));
    float dist = s_dist[t];
    float rden = fastrcp(dist + 1e-8f);
    float gts = s_gtd[t] - dist;
#pragma unroll
    for (int j = 0; j < 3; ++j) {
      float dir = s_dvec[t][j] * rden;
      atomicAdd(&ws[WS_SN + iN * 3 + j], score * dir * invc);
      atomicAdd(&ws[WS_GN + iN * 3 + j], gts * dir * invc);
    }
  }
}

// ---------------- per-node: loss terms, preds, center sums ----------------
__global__ void k_node2(const int* batch, float* ws) {
  int n = blockIdx.x * blockDim.x + threadIdx.x;
  if (n >= Nn) return;
  int b = batch[n];
  float sig = ws[WS_SIG + b];
#pragma unroll
  for (int j = 0; j < 3; ++j) {
    float s = ws[WS_SN + n * 3 + j], g = ws[WS_GN + n * 3 + j];
    float d = s - g / sig;
    atomicAdd(&ws[WS_BSUM + b * 3 + j], d * d);
    float pr = ws[WS_PERT + n * 3 + j] + s / sig;
    ws[WS_PREDS + n * 3 + j] = pr;
    atomicAdd(&ws[WS_CENTER + b * 3 + j], pr);
  }
}

// ---------------- per-node: global min/max of dc ----------------
__global__ void k_minmax(const int* batch, const int* num_atoms, float* ws) {
  int n = blockIdx.x * blockDim.x + threadIdx.x;
  int lane = threadIdx.x & 63, wid = threadIdx.x >> 6;
  float mx[3], mn[3];
  if (n < Nn) {
    int b = batch[n];
    float na = (float)num_atoms[b];
#pragma unroll
    for (int j = 0; j < 3; ++j) {
      float v = ws[WS_PREDS + n * 3 + j] - ws[WS_CENTER + b * 3 + j] / na;
      mx[j] = v; mn[j] = v;
    }
  } else {
#pragma unroll
    for (int j = 0; j < 3; ++j) { mx[j] = -3.0e38f; mn[j] = 3.0e38f; }
  }
#pragma unroll
  for (int off = 32; off >= 1; off >>= 1) {
#pragma unroll
    for (int j = 0; j < 3; ++j) {
      mx[j] = fmaxf(mx[j], __shfl_xor(mx[j], off));
      mn[j] = fminf(mn[j], __shfl_xor(mn[j], off));
    }
  }
  __shared__ float smx[4][3], smn[4][3];
  if (lane == 0) {
#pragma unroll
    for (int j = 0; j < 3; ++j) { smx[wid][j] = mx[j]; smn[wid][j] = mn[j]; }
  }
  __syncthreads();
  if (threadIdx.x == 0) {
#pragma unroll
    for (int j = 0; j < 3; ++j) {
      float M = fmaxf(fmaxf(smx[0][j], smx[1][j]), fmaxf(smx[2][j], smx[3][j]));
      float m = fminf(fminf(smn[0][j], smn[1][j]), fminf(smn[2][j], smn[3][j]));
      atomicMaxFloat(&ws[WS_MINMAX + j], M);
      atomicMinFloat(&ws[WS_MINMAX + 3 + j], m);
    }
  }
}

// ---------------- finalize (parallel over batches) ----------------
__global__ void k_final(const int* num_atoms, const float* ws, float* out) {
  int t = threadIdx.x;  // 128 threads
  float loss = 0.f;
  if (t < Bb) {
    float na = (float)num_atoms[t];
    loss = (ws[WS_BSUM + t * 3] + ws[WS_BSUM + t * 3 + 1] + ws[WS_BSUM + t * 3 + 2]) / na;
  }
#pragma unroll
  for (int off = 32; off >= 1; off >>= 1) loss += __shfl_xor(loss, off);
  __shared__ float s2[2];
  if ((t & 63) == 0) s2[t >> 6] = loss;
  __syncthreads();
  if (t == 0) {
    float L = (s2[0] + s2[1]) / (3.0f * (float)Bb);
    float pbs = fabsf(ws[WS_MINMAX + 0] + ws[WS_MINMAX + 3]) +
                fabsf(ws[WS_MINMAX + 1] + ws[WS_MINMAX + 4]) +
                fabsf(ws[WS_MINMAX + 2] + ws[WS_MINMAX + 5]);
    out[0] = L;
    out[1] = pbs;
  }
}

extern "C" void kernel_launch(void* const* d_in, const int* in_sizes, int n_in,
                              void* d_out, int out_size, void* d_ws, size_t ws_size,
                              hipStream_t stream) {
  const float* latents = (const float*)d_in[0];
  const float* gtf     = (const float*)d_in[1];
  const float* lengths = (const float*)d_in[2];
  const float* angles  = (const float*)d_in[3];
  const float* noise   = (const float*)d_in[4];
  const float* sigmas  = (const float*)d_in[5];
  const float* aemb    = (const float*)d_in[6];
  const float* rbfW    = (const float*)d_in[7];
  const float* rbfb    = (const float*)d_in[8];
  const float* bbW     = (const float*)d_in[9];
  const float* bbb     = (const float*)d_in[10];
  const float* scW0    = (const float*)d_in[11];
  const float* scb0    = (const float*)d_in[12];
  const float* scW1    = (const float*)d_in[13];
  const float* scb1    = (const float*)d_in[14];
  const float* scW2    = (const float*)d_in[15];
  const float* scb2    = (const float*)d_in[16];
  const int* num_atoms = (const int*)d_in[17];
  const int* atype     = (const int*)d_in[18];
  const int* batch     = (const int*)d_in[19];
  const int* ei        = (const int*)d_in[20];
  const int* toj       = (const int*)d_in[21];
  const int* tsteps    = (const int*)d_in[22];
  float* ws = (float*)d_ws;
  float* out = (float*)d_out;
  unsigned short* w0t = (unsigned short*)(ws + WS_W0T_F);
  unsigned short* w1t = (unsigned short*)(ws + WS_W1T_F);
  unsigned short* rbfw2t = (unsigned short*)(ws + WS_RBFW2T_F);

  hipLaunchKernelGGL(k_pre, dim3(746), dim3(256), 0, stream,
                     lengths, angles, sigmas, tsteps, aemb, bbW, rbfW, rbfb, bbb,
                     latents, scW0, scb0, scW1, gtf, noise, batch, atype,
                     w0t, w1t, rbfw2t, ws);
  hipLaunchKernelGGL(k_edge, dim3(Ee / TE), dim3(512), 0, stream,
                     ei, toj, batch, atype, w0t, w1t, rbfw2t, scb1, scW2, scb2, ws);
  hipLaunchKernelGGL(k_node2, dim3(50), dim3(256), 0, stream, batch, ws);
  hipLaunchKernelGGL(k_minmax, dim3(50), dim3(256), 0, stream, batch, num_atoms, ws);
  hipLaunchKernelGGL(k_final, dim3(1), dim3(128), 0, stream, num_atoms, ws, out);
}

// Round 15
// 267.324 us; speedup vs baseline: 1.3166x; 1.1795x over previous
//
#include <hip/hip_runtime.h>
#include <hip/hip_bf16.h>

// ---------------- problem constants ----------------
namespace {
constexpr int Bb = 128, Nn = 12800, Ee = 262144;
constexpr int LAT = 256, HID = 128, FCH = 512, NRBF = 16;
constexpr int TE = 64;        // edges per block (divides 2048 = edges/graph)
constexpr int TSTRIDE = 1040; // activation-tile stride in bytes
constexpr int RBF_OFF = 16640; // LDS byte offset of shared rbf B-frag tiles (4 KB)

// workspace offsets (floats)
constexpr int WS_L      = 0;        // B*9
constexpr int WS_LI     = 1152;     // B*9
constexpr int WS_SIG    = 2304;     // B
constexpr int WS_RBFW2  = 2432;     // 16*128
constexpr int WS_CVEC   = 4480;     // 128
constexpr int WS_HB     = 4608;     // 100*128
constexpr int WS_LATP   = 17408;    // B*512
constexpr int WS_PERT   = 82944;    // N*3
constexpr int WS_ALIGN  = 121344;   // N*3
constexpr int WS_SN     = 159744;   // N*3 (atomic)
constexpr int WS_GN     = 198144;   // N*3 (atomic)
constexpr int WS_PREDS  = 236544;   // N*3
constexpr int WS_BSUM   = 274944;   // B*3 (atomic)
constexpr int WS_CENTER = 275328;   // B*3 (atomic)
constexpr int WS_MINMAX = 275712;   // 6   (max x3, min x3)
// bf16 fragment-tiled weights (stored as ushort), float-index base:
constexpr int WS_W0T_F   = 276000;  // ushort[512*128]  (= 32768 floats)
constexpr int WS_W1T_F   = 308768;  // ushort[512*512]  (= 131072 floats)
constexpr int WS_RBFW2T_F = 439840; // ushort[8 tiles * 64 lanes * 8] (= 2048 floats)
}

typedef short bf16x8 __attribute__((ext_vector_type(8)));
typedef unsigned short u16x8 __attribute__((ext_vector_type(8)));
typedef float f32x4 __attribute__((ext_vector_type(4)));

static __device__ __forceinline__ unsigned short f2bf(float f) {
  unsigned int u = __float_as_uint(f);
  unsigned int r = (u + 0x7fffu + ((u >> 16) & 1u)) >> 16;
  return (unsigned short)r;
}
// single-instruction packed f32->bf16 pair: low16 = bf16(a), high16 = bf16(b)
static __device__ __forceinline__ unsigned int pk2bf(float a, float b) {
  unsigned int r;
  asm("v_cvt_pk_bf16_f32 %0, %1, %2" : "=v"(r) : "v"(a), "v"(b));
  return r;
}
static __device__ __forceinline__ float fastrcp(float x) {
  return __builtin_amdgcn_rcpf(x);
}

static __device__ __forceinline__ void make_lattice(
    const float* lengths, const float* angles, int b, float L[9], float Li[9]) {
  float a = lengths[b * 3 + 0], bl = lengths[b * 3 + 1], c = lengths[b * 3 + 2];
  const float d2r = 0.017453292519943295f;
  float al = angles[b * 3 + 0] * d2r, be = angles[b * 3 + 1] * d2r, ga = angles[b * 3 + 2] * d2r;
  float ca = cosf(al), cb = cosf(be), cg = cosf(ga), sa = sinf(al), sb = sinf(be);
  float val = (ca * cb - cg) / (sa * sb);
  val = fminf(1.f, fmaxf(-1.f, val));
  float gs = acosf(val);
  L[0] = a * sb;              L[1] = 0.f;                L[2] = a * cb;
  L[3] = -bl * sa * cosf(gs); L[4] = bl * sa * sinf(gs); L[5] = bl * ca;
  L[6] = 0.f;                 L[7] = 0.f;                L[8] = c;
  float det = L[0] * (L[4] * L[8] - L[5] * L[7])
            - L[1] * (L[3] * L[8] - L[5] * L[6])
            + L[2] * (L[3] * L[7] - L[4] * L[6]);
  float id = 1.f / det;
  Li[0] =  (L[4] * L[8] - L[5] * L[7]) * id;
  Li[1] = -(L[1] * L[8] - L[2] * L[7]) * id;
  Li[2] =  (L[1] * L[5] - L[2] * L[4]) * id;
  Li[3] = -(L[3] * L[8] - L[5] * L[6]) * id;
  Li[4] =  (L[0] * L[8] - L[2] * L[6]) * id;
  Li[5] = -(L[0] * L[5] - L[2] * L[3]) * id;
  Li[6] =  (L[3] * L[7] - L[4] * L[6]) * id;
  Li[7] = -(L[0] * L[7] - L[1] * L[6]) * id;
  Li[8] =  (L[0] * L[4] - L[1] * L[3]) * id;
}

static __device__ __forceinline__ void atomicMaxFloat(float* addr, float val) {
  int* ai = reinterpret_cast<int*>(addr);
  int old = *ai;
  while (__int_as_float(old) < val) {
    int assumed = old;
    old = atomicCAS(ai, assumed, __float_as_int(val));
    if (old == assumed) break;
  }
}
static __device__ __forceinline__ void atomicMinFloat(float* addr, float val) {
  int* ai = reinterpret_cast<int*>(addr);
  int old = *ai;
  while (__int_as_float(old) > val) {
    int assumed = old;
    old = atomicCAS(ai, assumed, __float_as_int(val));
    if (old == assumed) break;
  }
}

// ---------------- fused prologue: all mutually-independent prep work ----------------
// blocks   0..303 : zero accumulators, init MINMAX
// block      304  : lattice + sigma -> ws
// blocks 305..404 : hb = atom_emb @ bb_W
// block      405  : rbfW2 / cvec (cvec consumed by k_edge)
// blocks 406..533 : lat_proj
// blocks 534..565 : cvtW0 (coalesced 16B writes)
// blocks 566..693 : cvtW1 (coalesced 16B writes)
// blocks 694..695 : rbfw2t A-frag tiles (K padded 16->32)
// blocks 696..745 : per-node geometry (lattice recomputed inline per node)
__global__ __launch_bounds__(256) void k_pre(
    const float* lengths, const float* angles, const float* sigmas, const int* tsteps,
    const float* aemb, const float* bbW, const float* rbfW, const float* rbfb,
    const float* bbb, const float* latents, const float* scW0, const float* scb0,
    const float* scW1, const float* gtf, const float* noise, const int* batch,
    const int* atype, unsigned short* w0t, unsigned short* w1t,
    unsigned short* rbfw2t, float* ws) {
  const int blk = blockIdx.x, t = threadIdx.x;
  if (blk < 304) {
    int gid = blk * 256 + t;
    if (gid < 2 * Nn * 3) ws[WS_SN + gid] = 0.f;
    else if (gid < 2 * Nn * 3 + 2 * Bb * 3) ws[WS_BSUM + (gid - 2 * Nn * 3)] = 0.f;
    else if (gid < 2 * Nn * 3 + 2 * Bb * 3 + 3) ws[WS_MINMAX + (gid - 2 * Nn * 3 - 2 * Bb * 3)] = -3.0e38f;
    else if (gid < 2 * Nn * 3 + 2 * Bb * 3 + 6) ws[WS_MINMAX + (gid - 2 * Nn * 3 - 2 * Bb * 3)] = 3.0e38f;
  } else if (blk == 304) {
    int b = t;
    if (b >= Bb) return;
    float L[9], Li[9];
    make_lattice(lengths, angles, b, L, Li);
#pragma unroll
    for (int i = 0; i < 9; ++i) {
      ws[WS_L + b * 9 + i] = L[i];
      ws[WS_LI + b * 9 + i] = Li[i];
    }
    ws[WS_SIG + b] = sigmas[tsteps[b]];
  } else if (blk < 405) {
    int tile = blk - 305;
    if (t < HID) {
      float acc = 0.f;
      for (int k = 0; k < HID; ++k) acc += aemb[tile * HID + k] * bbW[k * HID + t];
      ws[WS_HB + tile * HID + t] = acc;
    }
  } else if (blk == 405) {
    if (t < HID) {
      float accs[NRBF];
#pragma unroll
      for (int k = 0; k < NRBF; ++k) accs[k] = 0.f;
      float accb = 0.f;
      for (int m = 0; m < HID; ++m) {
        float w = bbW[m * HID + t];
#pragma unroll
        for (int k = 0; k < NRBF; ++k) accs[k] += rbfW[k * HID + m] * w;
        accb += rbfb[m] * w;
      }
#pragma unroll
      for (int k = 0; k < NRBF; ++k) ws[WS_RBFW2 + k * HID + t] = accs[k];
      ws[WS_CVEC + t] = accb + bbb[t];
    }
  } else if (blk < 534) {
    int b = blk - 406;
    __shared__ float lat[LAT];
    lat[t] = latents[b * LAT + t];
    __syncthreads();
    int c0 = 2 * t;
    float a0 = 0.f, a1 = 0.f;
    for (int m = 0; m < LAT; ++m) {
      float2 w = *reinterpret_cast<const float2*>(scW0 + (HID + m) * FCH + c0);
      float lm = lat[m];
      a0 += lm * w.x;
      a1 += lm * w.y;
    }
    ws[WS_LATP + b * FCH + c0] = a0 + scb0[c0];
    ws[WS_LATP + b * FCH + c0 + 1] = a1 + scb0[c0 + 1];
  } else if (blk < 566) {
    int id8 = (blk - 534) * 256 + t;     // 0..8191
    int tile = id8 >> 6, lf = id8 & 63;  // tile = colTile*4 + kTile
    int colTile = tile >> 2, kTile = tile & 3;
    int col = colTile * 16 + (lf & 15);
    int kbase = kTile * 32 + (lf >> 4) * 8;
    u16x8 v;
#pragma unroll
    for (int e = 0; e < 8; ++e) v[e] = f2bf(scW0[(kbase + e) * FCH + col]);
    *(u16x8*)(w0t + id8 * 8) = v;
  } else if (blk < 694) {
    int id8 = (blk - 566) * 256 + t;     // 0..32767
    int tile = id8 >> 6, lf = id8 & 63;  // tile = colTile*16 + kTile
    int colTile = tile >> 4, kTile = tile & 15;
    int col = colTile * 16 + (lf & 15);
    int kbase = kTile * 32 + (lf >> 4) * 8;
    u16x8 v;
#pragma unroll
    for (int e = 0; e < 8; ++e) v[e] = f2bf(scW1[(kbase + e) * FCH + col]);
    *(u16x8*)(w1t + id8 * 8) = v;
  } else if (blk < 696) {
    // rbfw2t: A-frag tiles of rbfW2^T (8 colTiles, K padded 16->32)
    int id = (blk - 694) * 256 + t;      // 0..511
    if (id < 512) {
      int tile = id >> 6, lf = id & 63;  // tile = colTile 0..7
      int c = tile * 16 + (lf & 15);
      u16x8 v;
#pragma unroll
      for (int e = 0; e < 8; ++e) {
        int k = (lf >> 4) * 8 + e;
        if (k < NRBF) {
          float acc = 0.f;
          for (int m = 0; m < HID; ++m) acc += rbfW[k * HID + m] * bbW[m * HID + c];
          v[e] = f2bf(acc);
        } else {
          v[e] = 0;
        }
      }
      *(u16x8*)(rbfw2t + id * 8) = v;
    }
  } else {
    // per-node geometry, lattice recomputed inline
    int n = (blk - 696) * 256 + t;
    if (n >= Nn) return;
    int b = batch[n];
    float L[9], Li[9];
    make_lattice(lengths, angles, b, L, Li);
    float sig = sigmas[tsteps[b]];
    float f0 = gtf[n * 3], f1 = gtf[n * 3 + 1], f2 = gtf[n * 3 + 2];
    float cg[3], p0[3], fp[3], pe[3], fg[3], fd[3];
#pragma unroll
    for (int j = 0; j < 3; ++j) cg[j] = f0 * L[j] + f1 * L[3 + j] + f2 * L[6 + j];
#pragma unroll
    for (int j = 0; j < 3; ++j) p0[j] = cg[j] + sig * noise[n * 3 + j];
#pragma unroll
    for (int j = 0; j < 3; ++j) {
      float v = p0[0] * Li[j] + p0[1] * Li[3 + j] + p0[2] * Li[6 + j];
      fp[j] = v - floorf(v);
    }
#pragma unroll
    for (int j = 0; j < 3; ++j) pe[j] = fp[0] * L[j] + fp[1] * L[3 + j] + fp[2] * L[6 + j];
#pragma unroll
    for (int j = 0; j < 3; ++j) fg[j] = cg[0] * Li[j] + cg[1] * Li[3 + j] + cg[2] * Li[6 + j];
#pragma unroll
    for (int j = 0; j < 3; ++j) { float d = fg[j] - fp[j]; fd[j] = d - rintf(d); }
#pragma unroll
    for (int j = 0; j < 3; ++j) {
      ws[WS_PERT + n * 3 + j] = pe[j];
      ws[WS_ALIGN + n * 3 + j] = pe[j] + fd[0] * L[j] + fd[1] * L[3 + j] + fd[2] * L[6 + j];
    }
  }
}

// ---------------- the big fused MFMA edge kernel (transposed compute) ----------------
// D[wcol][edge] = mfma(A = W^T fragment, B = act^T fragment). Activations in LDS
// in B-fragment tile order at TSTRIDE-byte stride; every ds_read = lane*16B.
// Tile: 64 edges x 512 cols, 8 waves; wave wv owns wcols [wv*64, wv*64+64).
// Phase B MFMA-ized (rbf@rbfW2); the rbf B-fragments are IDENTICAL across all
// 8 waves, so wave 0 computes them ONCE in Phase A (dist shared via __shfl)
// into LDS bytes [RBF_OFF, RBF_OFF+4096) — a region dead before the Phase-C
// epilogue overwrites it. LDS ~70 KB -> 2 blocks/CU.
__global__ __launch_bounds__(512, 4) void k_edge(
    const int* ei, const int* toj, const int* batch, const int* atype,
    const unsigned short* w0t, const unsigned short* w1t,
    const unsigned short* rbfw2t,
    const float* scb1, const float* scW2, const float* scb2, float* ws) {
  __shared__ __align__(16) char s_hh_b[64 * TSTRIDE];  // 66560 B
  __shared__ float s_dvec[TE][3];
  __shared__ float s_dist[TE], s_gtd[TE];
  __shared__ int s_tj[TE], s_ti[TE];
  __shared__ float s_wsum[8][TE];             // 2 KB

  char* s_ef_b = s_hh_b;                      // tiles 0..15

  const int t = threadIdx.x;
  const int e0 = blockIdx.x * TE;
  const int b0 = batch[ei[e0]];

  const int lane = t & 63;
  const int wv = t >> 6;        // 0..7
  const int el = lane & 15;     // edge-in-tile (D col / B-frag edge)
  const int q  = lane >> 4;     // k-octet group

  // ---- Phase A: per-edge geometry (wave 0) + shared rbf B-frag build
  if (t < TE) {
    int e = e0 + t;
    int jn = ei[e], iN = ei[Ee + e];
    int b = batch[jn];
    float tx = (float)toj[e * 3], ty = (float)toj[e * 3 + 1], tz = (float)toj[e * 3 + 2];
    const float* L = ws + WS_L + b * 9;
    float dv[3], gv[3];
#pragma unroll
    for (int j = 0; j < 3; ++j) {
      float off = tx * L[j] + ty * L[3 + j] + tz * L[6 + j];
      dv[j] = ws[WS_PERT + iN * 3 + j] - ws[WS_PERT + jn * 3 + j] - off;
      gv[j] = ws[WS_ALIGN + iN * 3 + j] - ws[WS_ALIGN + jn * 3 + j] - off;
    }
    float dist = sqrtf(dv[0] * dv[0] + dv[1] * dv[1] + dv[2] * dv[2]);
    float gtd = sqrtf(gv[0] * gv[0] + gv[1] * gv[1] + gv[2] * gv[2]);
#pragma unroll
    for (int j = 0; j < 3; ++j) s_dvec[t][j] = dv[j];
    s_dist[t] = dist;
    s_gtd[t] = gtd;
    s_tj[t] = atype[jn]; s_ti[t] = atype[iN];
    // shared rbf B-fragments: tile n holds B[k][edge n*16+el]; this lane (el0,q0)
    // supplies k-octet q0 (zeros for the K-pad octets 2,3).
    const float step = 7.0f / 15.0f;
    int el0 = t & 15, q0 = t >> 4;
#pragma unroll
    for (int n = 0; n < 4; ++n) {
      float dn = __shfl(dist, n * 16 + el0);
      unsigned int wb0 = 0, wb1 = 0, wb2 = 0, wb3 = 0;
      if (q0 < 2) {
        float d0 = dn - (float)(8 * q0) * step;
#pragma unroll
        for (int p = 0; p < 4; ++p) {
          float m0 = d0 - (float)(2 * p) * step;
          float m1 = m0 - step;
          unsigned int r = pk2bf(__expf(-10.f * m0 * m0), __expf(-10.f * m1 * m1));
          if (p == 0) wb0 = r; else if (p == 1) wb1 = r;
          else if (p == 2) wb2 = r; else wb3 = r;
        }
      }
      uint4 u = {wb0, wb1, wb2, wb3};
      *(uint4*)(s_hh_b + RBF_OFF + n * 1024 + t * 16) = u;
    }
  }
  __syncthreads();

  // ---- Phase B (MFMA): ef = silu(rbf@rbfW2 + hb[tj] + hb[ti] + cvec) -> s_efT
  // Wave wv owns hid colTile wv (cols wv*16 .. wv*16+15) x 4 edgeTiles.
  {
    bf16x8 arb = *(const bf16x8*)(rbfw2t + wv * 512 + lane * 8);
    bf16x8 brb[4];
#pragma unroll
    for (int n = 0; n < 4; ++n)
      brb[n] = *(const bf16x8*)(s_hh_b + RBF_OFF + n * 1024 + lane * 16);
    f32x4 accB[4];
#pragma unroll
    for (int n = 0; n < 4; ++n)
      accB[n] = __builtin_amdgcn_mfma_f32_16x16x32_bf16(
          arb, brb[n], (f32x4){0.f, 0.f, 0.f, 0.f}, 0, 0, 0);
    // epilogue: lane holds D[col = wv*16 + q*4 + r][edge = n*16 + el]
    int col0 = wv * 16 + q * 4;
    float4 cv = *(const float4*)(ws + WS_CVEC + col0);
    int kT = wv >> 1;
    int oct = (wv & 1) * 2 + (q >> 1);
#pragma unroll
    for (int n = 0; n < 4; ++n) {
      int eg = n * 16 + el;
      int tj = s_tj[eg], ti = s_ti[eg];
      float4 hj = *(const float4*)(ws + WS_HB + tj * HID + col0);
      float4 hi = *(const float4*)(ws + WS_HB + ti * HID + col0);
      f32x4 a = accB[n];
      float z0 = a[0] + hj.x + hi.x + cv.x;
      float z1 = a[1] + hj.y + hi.y + cv.y;
      float z2 = a[2] + hj.z + hi.z + cv.z;
      float z3 = a[3] + hj.w + hi.w + cv.w;
      float s0 = z0 * fastrcp(1.f + __expf(-z0));
      float s1 = z1 * fastrcp(1.f + __expf(-z1));
      float s2 = z2 * fastrcp(1.f + __expf(-z2));
      float s3 = z3 * fastrcp(1.f + __expf(-z3));
      uint2 val = {pk2bf(s0, s1), pk2bf(s2, s3)};
      int addr = (kT * 4 + n) * TSTRIDE + (el + 16 * oct) * 16 + (q & 1) * 8;
      *(uint2*)(s_ef_b + addr) = val;
    }
  }
  __syncthreads();

  // ---- Phase C: GEMM1^T  hh^T = relu(W0a^T @ ef^T + latp) -> s_hhT (B-frag tiles)
  {
    f32x4 acc[4][4];  // [m = wcolTile][n = edgeTile]
#pragma unroll
    for (int m = 0; m < 4; ++m)
#pragma unroll
      for (int n = 0; n < 4; ++n) acc[m][n] = (f32x4){0.f, 0.f, 0.f, 0.f};
    const unsigned short* w0base = w0t + (size_t)(wv * 4) * 4 * 512 + lane * 8;
#pragma unroll
    for (int kt = 0; kt < 4; ++kt) {
      bf16x8 aw[4];
#pragma unroll
      for (int m = 0; m < 4; ++m)
        aw[m] = *(const bf16x8*)(w0base + (size_t)(m * 4 + kt) * 512);
      bf16x8 bf[4];
#pragma unroll
      for (int n = 0; n < 4; ++n)
        bf[n] = *(const bf16x8*)(s_ef_b + (kt * 4 + n) * TSTRIDE + lane * 16);
      __builtin_amdgcn_s_setprio(1);
#pragma unroll
      for (int n = 0; n < 4; ++n)
#pragma unroll
        for (int m = 0; m < 4; ++m)
          acc[m][n] = __builtin_amdgcn_mfma_f32_16x16x32_bf16(aw[m], bf[n], acc[m][n], 0, 0, 0);
      __builtin_amdgcn_s_setprio(0);
    }
    __syncthreads();   // ALL s_efT/rbf reads complete before s_hhT overwrites the alias
    // Epilogue: lane holds D[wcol = m*16 + q*4 + r][edge = n*16 + el].
#pragma unroll
    for (int m = 0; m < 4; ++m) {
      float4 lp = *(const float4*)(ws + WS_LATP + b0 * FCH + wv * 64 + m * 16 + q * 4);
#pragma unroll
      for (int n = 0; n < 4; ++n) {
        f32x4 v = acc[m][n];
        float h0 = fmaxf(v[0] + lp.x, 0.f);
        float h1 = fmaxf(v[1] + lp.y, 0.f);
        float h2 = fmaxf(v[2] + lp.z, 0.f);
        float h3 = fmaxf(v[3] + lp.w, 0.f);
        uint2 val = {pk2bf(h0, h1), pk2bf(h2, h3)};
        int kT = wv * 2 + (m >> 1);
        int oct = (m & 1) * 2 + (q >> 1);
        int addr = (kT * 4 + n) * TSTRIDE + (el + 16 * oct) * 16 + (q & 1) * 8;
        *(uint2*)(s_hh_b + addr) = val;
      }
    }
  }
  __syncthreads();

  // ---- Phase D: GEMM2^T + fused score reduction
  {
    f32x4 acc[4][4];  // [m = w1colTile][n = edgeTile]
#pragma unroll
    for (int m = 0; m < 4; ++m)
#pragma unroll
      for (int n = 0; n < 4; ++n) acc[m][n] = (f32x4){0.f, 0.f, 0.f, 0.f};
    const unsigned short* w1base = w1t + (size_t)(wv * 4) * 16 * 512 + lane * 8;
#pragma unroll 4
    for (int kt = 0; kt < 16; ++kt) {
      bf16x8 aw[4];
#pragma unroll
      for (int m = 0; m < 4; ++m)
        aw[m] = *(const bf16x8*)(w1base + (size_t)(m * 16 + kt) * 512);
      bf16x8 bf[4];
#pragma unroll
      for (int n = 0; n < 4; ++n)
        bf[n] = *(const bf16x8*)(s_hh_b + (kt * 4 + n) * TSTRIDE + lane * 16);
      __builtin_amdgcn_s_setprio(1);
#pragma unroll
      for (int n = 0; n < 4; ++n)
#pragma unroll
        for (int m = 0; m < 4; ++m)
          acc[m][n] = __builtin_amdgcn_mfma_f32_16x16x32_bf16(aw[m], bf[n], acc[m][n], 0, 0, 0);
      __builtin_amdgcn_s_setprio(0);
    }
    // hh1 = relu(acc + b1); p[edge] += hh1 * W2, reduced over w1cols
    float p[4] = {0.f, 0.f, 0.f, 0.f};   // per edgeTile n
#pragma unroll
    for (int m = 0; m < 4; ++m) {
      int colb = wv * 64 + m * 16 + q * 4;
      float4 b1v = *(const float4*)(scb1 + colb);
      float4 w2v = *(const float4*)(scW2 + colb);
#pragma unroll
      for (int n = 0; n < 4; ++n) {
        f32x4 v = acc[m][n];
        p[n] += fmaxf(v[0] + b1v.x, 0.f) * w2v.x;
        p[n] += fmaxf(v[1] + b1v.y, 0.f) * w2v.y;
        p[n] += fmaxf(v[2] + b1v.z, 0.f) * w2v.z;
        p[n] += fmaxf(v[3] + b1v.w, 0.f) * w2v.w;
      }
    }
    // reduce over q (lane bits 4..5)
#pragma unroll
    for (int n = 0; n < 4; ++n) {
      float x = p[n];
      x += __shfl_xor(x, 16);
      x += __shfl_xor(x, 32);
      p[n] = x;
    }
    if (lane < 16) {
#pragma unroll
      for (int n = 0; n < 4; ++n) s_wsum[wv][n * 16 + el] = p[n];
    }
  }
  __syncthreads();

  // ---- Phase E: segment-mean scatter (threads 0..63)
  if (t < TE) {
    int e = e0 + t;
    float score = scb2[0];
#pragma unroll
    for (int w = 0; w < 8; ++w) score += s_wsum[w][t];
    int jn = ei[e], iN = ei[Ee + e];
    int s = e;
    while (s > 0 && ei[s - 1] == jn && ei[Ee + s - 1] == iN) --s;
    int en = e;
    while (en + 1 < Ee && ei[en + 1] == jn && ei[Ee + en + 1] == iN) ++en;
    float invc = fastrcp((float)(en - s + 1));
    float dist = s_dist[t];
    float rden = fastrcp(dist + 1e-8f);
    float gts = s_gtd[t] - dist;
#pragma unroll
    for (int j = 0; j < 3; ++j) {
      float dir = s_dvec[t][j] * rden;
      atomicAdd(&ws[WS_SN + iN * 3 + j], score * dir * invc);
      atomicAdd(&ws[WS_GN + iN * 3 + j], gts * dir * invc);
    }
  }
}

// ---------------- per-node: loss terms, preds, center sums ----------------
// Nodes are graph-contiguous (100/graph); a 64-lane wave of consecutive nodes
// spans at most TWO graphs -> exact two-segment wave reduction, then one
// atomicAdd per (segment, component) instead of one per node (64x fewer
// atomics onto the 768 hot addresses).
__global__ void k_node2(const int* batch, float* ws) {
  int n = blockIdx.x * blockDim.x + threadIdx.x;   // grid covers exactly Nn
  int lane = threadIdx.x & 63;
  int b = batch[n];
  float sig = ws[WS_SIG + b];
  float v[6];
#pragma unroll
  for (int j = 0; j < 3; ++j) {
    float s = ws[WS_SN + n * 3 + j], g = ws[WS_GN + n * 3 + j];
    float d = s - g / sig;
    v[j] = d * d;
    float pr = ws[WS_PERT + n * 3 + j] + s / sig;
    ws[WS_PREDS + n * 3 + j] = pr;
    v[3 + j] = pr;
  }
  int g0 = __shfl(b, 0);
  bool in0 = (b == g0);
  unsigned long long m1 = __ballot(!in0);
#pragma unroll
  for (int seg = 0; seg < 2; ++seg) {
    int gs, leader;
    bool inseg;
    if (seg == 0) {
      gs = g0; leader = 0; inseg = in0;
    } else {
      if (m1 == 0ULL) break;
      leader = __ffsll(m1) - 1;
      gs = __shfl(b, leader);
      inseg = !in0;
    }
    float sv[6];
#pragma unroll
    for (int k = 0; k < 6; ++k) {
      float x = inseg ? v[k] : 0.f;
      x += __shfl_xor(x, 1);
      x += __shfl_xor(x, 2);
      x += __shfl_xor(x, 4);
      x += __shfl_xor(x, 8);
      x += __shfl_xor(x, 16);
      x += __shfl_xor(x, 32);
      sv[k] = x;
    }
    if (lane == leader) {
#pragma unroll
      for (int j = 0; j < 3; ++j) {
        atomicAdd(&ws[WS_BSUM + gs * 3 + j], sv[j]);
        atomicAdd(&ws[WS_CENTER + gs * 3 + j], sv[3 + j]);
      }
    }
  }
}

// ---------------- per-node: global min/max of dc ----------------
__global__ void k_minmax(const int* batch, const int* num_atoms, float* ws) {
  int n = blockIdx.x * blockDim.x + threadIdx.x;
  int lane = threadIdx.x & 63, wid = threadIdx.x >> 6;
  float mx[3], mn[3];
  if (n < Nn) {
    int b = batch[n];
    float na = (float)num_atoms[b];
#pragma unroll
    for (int j = 0; j < 3; ++j) {
      float v = ws[WS_PREDS + n * 3 + j] - ws[WS_CENTER + b * 3 + j] / na;
      mx[j] = v; mn[j] = v;
    }
  } else {
#pragma unroll
    for (int j = 0; j < 3; ++j) { mx[j] = -3.0e38f; mn[j] = 3.0e38f; }
  }
#pragma unroll
  for (int off = 32; off >= 1; off >>= 1) {
#pragma unroll
    for (int j = 0; j < 3; ++j) {
      mx[j] = fmaxf(mx[j], __shfl_xor(mx[j], off));
      mn[j] = fminf(mn[j], __shfl_xor(mn[j], off));
    }
  }
  __shared__ float smx[4][3], smn[4][3];
  if (lane == 0) {
#pragma unroll
    for (int j = 0; j < 3; ++j) { smx[wid][j] = mx[j]; smn[wid][j] = mn[j]; }
  }
  __syncthreads();
  if (threadIdx.x == 0) {
#pragma unroll
    for (int j = 0; j < 3; ++j) {
      float M = fmaxf(fmaxf(smx[0][j], smx[1][j]), fmaxf(smx[2][j], smx[3][j]));
      float m = fminf(fminf(smn[0][j], smn[1][j]), fminf(smn[2][j], smn[3][j]));
      atomicMaxFloat(&ws[WS_MINMAX + j], M);
      atomicMinFloat(&ws[WS_MINMAX + 3 + j], m);
    }
  }
}

// ---------------- finalize (parallel over batches) ----------------
__global__ void k_final(const int* num_atoms, const float* ws, float* out) {
  int t = threadIdx.x;  // 128 threads
  float loss = 0.f;
  if (t < Bb) {
    float na = (float)num_atoms[t];
    loss = (ws[WS_BSUM + t * 3] + ws[WS_BSUM + t * 3 + 1] + ws[WS_BSUM + t * 3 + 2]) / na;
  }
#pragma unroll
  for (int off = 32; off >= 1; off >>= 1) loss += __shfl_xor(loss, off);
  __shared__ float s2[2];
  if ((t & 63) == 0) s2[t >> 6] = loss;
  __syncthreads();
  if (t == 0) {
    float L = (s2[0] + s2[1]) / (3.0f * (float)Bb);
    float pbs = fabsf(ws[WS_MINMAX + 0] + ws[WS_MINMAX + 3]) +
                fabsf(ws[WS_MINMAX + 1] + ws[WS_MINMAX + 4]) +
                fabsf(ws[WS_MINMAX + 2] + ws[WS_MINMAX + 5]);
    out[0] = L;
    out[1] = pbs;
  }
}

extern "C" void kernel_launch(void* const* d_in, const int* in_sizes, int n_in,
                              void* d_out, int out_size, void* d_ws, size_t ws_size,
                              hipStream_t stream) {
  const float* latents = (const float*)d_in[0];
  const float* gtf     = (const float*)d_in[1];
  const float* lengths = (const float*)d_in[2];
  const float* angles  = (const float*)d_in[3];
  const float* noise   = (const float*)d_in[4];
  const float* sigmas  = (const float*)d_in[5];
  const float* aemb    = (const float*)d_in[6];
  const float* rbfW    = (const float*)d_in[7];
  const float* rbfb    = (const float*)d_in[8];
  const float* bbW     = (const float*)d_in[9];
  const float* bbb     = (const float*)d_in[10];
  const float* scW0    = (const float*)d_in[11];
  const float* scb0    = (const float*)d_in[12];
  const float* scW1    = (const float*)d_in[13];
  const float* scb1    = (const float*)d_in[14];
  const float* scW2    = (const float*)d_in[15];
  const float* scb2    = (const float*)d_in[16];
  const int* num_atoms = (const int*)d_in[17];
  const int* atype     = (const int*)d_in[18];
  const int* batch     = (const int*)d_in[19];
  const int* ei        = (const int*)d_in[20];
  const int* toj       = (const int*)d_in[21];
  const int* tsteps    = (const int*)d_in[22];
  float* ws = (float*)d_ws;
  float* out = (float*)d_out;
  unsigned short* w0t = (unsigned short*)(ws + WS_W0T_F);
  unsigned short* w1t = (unsigned short*)(ws + WS_W1T_F);
  unsigned short* rbfw2t = (unsigned short*)(ws + WS_RBFW2T_F);

  hipLaunchKernelGGL(k_pre, dim3(746), dim3(256), 0, stream,
                     lengths, angles, sigmas, tsteps, aemb, bbW, rbfW, rbfb, bbb,
                     latents, scW0, scb0, scW1, gtf, noise, batch, atype,
                     w0t, w1t, rbfw2t, ws);
  hipLaunchKernelGGL(k_edge, dim3(Ee / TE), dim3(512), 0, stream,
                     ei, toj, batch, atype, w0t, w1t, rbfw2t, scb1, scW2, scb2, ws);
  hipLaunchKernelGGL(k_node2, dim3(50), dim3(256), 0, stream, batch, ws);
  hipLaunchKernelGGL(k_minmax, dim3(50), dim3(256), 0, stream, batch, num_atoms, ws);
  hipLaunchKernelGGL(k_final, dim3(1), dim3(128), 0, stream, num_atoms, ws, out);
}